// Round 1
// baseline (297.920 us; speedup 1.0000x reference)
//
#include <hip/hip_runtime.h>
#include <hip/hip_bf16.h>

// Problem constants (from reference setup_inputs): B=60, T=4, K=100, 1M docs.
#define T_DIM 4
#define K_DIM 100
#define NPER 400          // T*K entries per row
#define NDOCS 1000000
#define FILL_BLOCK 256
#define FILL_PER_THREAD 32
#define FILL_CHUNK (FILL_BLOCK * FILL_PER_THREAD)               // 8192 elements
#define BLOCKS_PER_ROW ((NDOCS + FILL_CHUNK - 1) / FILL_CHUNK)  // 123 (tail=576)
#define QN (FILL_PER_THREAD / 4)                                // 8 int4 per thread

// -------- Kernel 1: per-row preprocessing (tiny) ------------------------
// Produces, per row b:
//   wsA[b*NPER + i]    = S[i] - i  (S = unique nonzero doc ids, ascending), i < nnz
//   wsHead[b*NPER + i] = i-th doc in (-score, id) order, i < nnz
//   wsNnz[b]           = nnz
//   out_pos[b]         = head[pos_positions[b]]   (positive_idx output)
__global__ __launch_bounds__(512) void rrf_prep_kernel(
    const int* __restrict__ idx, const float* __restrict__ rnk,
    const float* __restrict__ weight, const int* __restrict__ pos,
    int* __restrict__ wsA, int* __restrict__ wsHead, int* __restrict__ wsNnz,
    int* __restrict__ out_pos)
{
  const int b = blockIdx.x;
  const int tid = threadIdx.x;
  const int lane = tid & 63, wave = tid >> 6;

  __shared__ int   ids[NPER];
  __shared__ float sc[NPER];
  __shared__ int   sid[NPER];
  __shared__ float ssc[NPER];
  __shared__ int   uid[NPER];
  __shared__ float usc[NPER];
  __shared__ int   head[NPER];
  __shared__ int   wsum[8];

  // Load ids + compute rrf scores: w_t / (60 + rank)
  if (tid < NPER) {
    ids[tid] = idx[b * NPER + tid];
    sc[tid]  = weight[tid / K_DIM] / (60.0f + rnk[b * NPER + tid]);
  }
  __syncthreads();

  // Rank-sort by (id, original position) -> groups duplicates adjacently,
  // duplicate scores kept in original-position order for summation.
  if (tid < NPER) {
    const int myid = ids[tid];
    int r = 0;
    for (int j = 0; j < NPER; ++j) {
      const int oj = ids[j];
      r += (oj < myid) || (oj == myid && j < tid);
    }
    sid[r] = myid;
    ssc[r] = sc[tid];
  }
  __syncthreads();

  // Leaders sum their duplicate run (in original-position order).
  int isLeader = 0;
  float mysum = 0.0f;
  if (tid < NPER) {
    isLeader = (tid == 0) || (sid[tid] != sid[tid - 1]);
    if (isLeader) {
      mysum = ssc[tid];
      for (int k = tid + 1; k < NPER && sid[k] == sid[tid]; ++k) mysum += ssc[k];
    }
  }

  // Inclusive scan of isLeader over 512 threads: shuffle wave scan + combine.
  int val = isLeader;
#pragma unroll
  for (int off = 1; off < 64; off <<= 1) {
    int n = __shfl_up(val, off, 64);
    if (lane >= off) val += n;
  }
  if (lane == 63) wsum[wave] = val;
  __syncthreads();
  if (wave == 0 && lane < 8) {
    int wv = wsum[lane];
#pragma unroll
    for (int off = 1; off < 8; off <<= 1) {
      int n = __shfl_up(wv, off, 8);
      if ((lane & 7) >= off) wv += n;
    }
    wsum[lane] = wv;     // inclusive per-wave totals
  }
  __syncthreads();
  const int incl = val + (wave > 0 ? wsum[wave - 1] : 0);
  const int nnz  = wsum[7];

  if (isLeader) {
    const int u = incl - 1;        // compacted slot; ascending id order preserved
    uid[u] = sid[tid];
    usc[u] = mysum;
  }
  __syncthreads();

  // Rank-sort uniques by (-score, id asc) == stable argsort(-fused) order.
  if (tid < nnz) {
    const float si = usc[tid];
    const int   ii = uid[tid];
    int r2 = 0;
    for (int j = 0; j < nnz; ++j) {
      const float sj = usc[j];
      r2 += (sj > si) || (sj == si && uid[j] < ii);
    }
    head[r2] = ii;
  }
  __syncthreads();

  if (tid < nnz) {
    wsA[b * NPER + tid]    = uid[tid] - tid;  // A[i] = S[i]-i, non-decreasing
    wsHead[b * NPER + tid] = head[tid];
  }
  if (tid == 0) {
    wsNnz[b]   = nnz;
    out_pos[b] = head[pos[b]];   // pos in [0,5), nnz >= ~396 always
  }
}

// -------- Kernel 2: write order[B, NDOCS] (the 240 MB store) ------------
// order[p] = head[p] for p < nnz; else z = p - nnz, doc = z + count{A[i] <= z}.
//
// Fast path (all chunks except 0 and tail): count{A <= z} across a whole
// 8192-element chunk changes by only nb = j1-j0 (~3 avg), where
//   j0 = count{A < z0}       (z0 = chunkbase - nnz, block-uniform)
//   j1 = count{A <= z0+8191}
// Both are found by two BLOCK-UNIFORM binary searches (broadcast LDS reads,
// conflict-free, one dependent chain shared by the whole block). Each element
// is then a pure ramp value z + j0 plus nb register compare-adds — no
// per-element dependent LDS search (was 9 dependent reads per int4).
//
// Block-strided int4 layout: thread t's q-th int4 sits at int4-index
// chunk*2048 + q*256 + t -> each store instruction covers a contiguous
// 1 KB/wave (16 B/lane), full-line coverage.
// Normal (allocating) stores: 240 MB output fits the 256 MiB L3; writeback
// drains after kernel end, overlapped with subsequent stream work.
__global__ __launch_bounds__(FILL_BLOCK) void rrf_fill_kernel(
    const int* __restrict__ wsA, const int* __restrict__ wsHead,
    const int* __restrict__ wsNnz, int* __restrict__ out)
{
  const int row   = blockIdx.x / BLOCKS_PER_ROW;
  const int chunk = blockIdx.x % BLOCKS_PER_ROW;
  const int tid   = threadIdx.x;

  __shared__ int A[NPER];
  __shared__ int H[NPER];
  __shared__ int s_nnz;

  // A needed by every block; H only by chunk 0 (positions < nnz ~ 400).
  for (int i = tid; i < NPER; i += FILL_BLOCK)
    A[i] = wsA[row * NPER + i];          // entries >= nnz are garbage, never read
  if (chunk == 0)
    for (int i = tid; i < NPER; i += FILL_BLOCK)
      H[i] = wsHead[row * NPER + i];
  if (tid == 0) s_nnz = wsNnz[row];
  __syncthreads();
  const int nnz = s_nnz;

  const int chunkbase = chunk * FILL_CHUNK;
  int* outrow = out + (long long)row * NDOCS;

  if (chunkbase >= nnz && chunk + 1 < BLOCKS_PER_ROW) {
    // Fast path: full chunk, pure zero-tail (chunks 1..121; nnz<400<8192).
    const int z0   = chunkbase - nnz;
    const int zend = z0 + FILL_CHUNK - 1;

    // Two block-uniform binary searches (broadcast LDS reads).
    int lo = 0, hi = nnz;
    while (lo < hi) { const int mid = (lo + hi) >> 1; if (A[mid] < z0) lo = mid + 1; else hi = mid; }
    const int j0 = lo;                   // count{A < z0}
    hi = nnz;                            // lo already == j0; A[k<j0] all < z0
    while (lo < hi) { const int mid = (lo + hi) >> 1; if (A[mid] <= zend) lo = mid + 1; else hi = mid; }
    const int j1 = lo;                   // count{A <= zend}

    const int za = z0 + tid * 4;         // this thread's first z (q=0)
    int v[QN][4];
#pragma unroll
    for (int q = 0; q < QN; ++q) {
      const int b = za + q * 1024 + j0;  // ramp base: z + j0
      v[q][0] = b; v[q][1] = b + 1; v[q][2] = b + 2; v[q][3] = b + 3;
    }
    // Breakpoint sweep: nb = j1-j0 (~3 avg) broadcast reads, 32 adds each.
    for (int k = j0; k < j1; ++k) {
      const int a = A[k];                // broadcast, conflict-free
#pragma unroll
      for (int q = 0; q < QN; ++q) {
        const int z = za + q * 1024;
        v[q][0] += (a <= z);
        v[q][1] += (a <= z + 1);
        v[q][2] += (a <= z + 2);
        v[q][3] += (a <= z + 3);
      }
    }
#pragma unroll
    for (int q = 0; q < QN; ++q)
      *reinterpret_cast<int4*>(outrow + chunkbase + q * 1024 + tid * 4) =
          make_int4(v[q][0], v[q][1], v[q][2], v[q][3]);
  } else {
    // Generic path: chunk 0 (head region) and the 576-element tail chunk.
#pragma unroll
    for (int q = 0; q < QN; ++q) {
      const int p0 = chunkbase + q * 1024 + tid * 4;
      if (p0 >= NDOCS) continue;         // tail: 576 = 144 int4s, all-or-none
      int vv[4];
#pragma unroll
      for (int k = 0; k < 4; ++k) {
        const int p = p0 + k;
        if (p < nnz) vv[k] = H[p];
        else {
          const int z = p - nnz;
          int lo = 0, hi = nnz;
          while (lo < hi) { const int mid = (lo + hi) >> 1; if (A[mid] <= z) lo = mid + 1; else hi = mid; }
          vv[k] = z + lo;
        }
      }
      *reinterpret_cast<int4*>(outrow + p0) = make_int4(vv[0], vv[1], vv[2], vv[3]);
    }
  }
}

extern "C" void kernel_launch(void* const* d_in, const int* in_sizes, int n_in,
                              void* d_out, int out_size, void* d_ws, size_t ws_size,
                              hipStream_t stream) {
  const int*   idx    = (const int*)d_in[0];    // [B,T,K] int32
  const float* rnk    = (const float*)d_in[1];  // [B,T,K] f32
  const float* weight = (const float*)d_in[2];  // [T] f32
  const int*   pos    = (const int*)d_in[3];    // [B] int32
  const int B = in_sizes[3];                    // 60

  int* out = (int*)d_out;                       // order[B*NDOCS] ++ positive_idx[B], int32
  int* ws  = (int*)d_ws;
  int* wsA    = ws;                             // B*NPER ints
  int* wsHead = ws + (size_t)B * NPER;          // B*NPER ints
  int* wsNnz  = ws + (size_t)2 * B * NPER;      // B ints   (~192 KB total)

  rrf_prep_kernel<<<B, 512, 0, stream>>>(idx, rnk, weight, pos,
                                         wsA, wsHead, wsNnz,
                                         out + (size_t)B * NDOCS);
  rrf_fill_kernel<<<B * BLOCKS_PER_ROW, FILL_BLOCK, 0, stream>>>(wsA, wsHead, wsNnz, out);
}

// Round 2
// 270.736 us; speedup vs baseline: 1.1004x; 1.1004x over previous
//
#include <hip/hip_runtime.h>
#include <hip/hip_bf16.h>

// Problem constants (from reference setup_inputs): B=60, T=4, K=100, 1M docs.
#define T_DIM 4
#define K_DIM 100
#define NPER 400          // T*K entries per row
#define NDOCS 1000000
#define FILL_BLOCK 256
#define FILL_PER_THREAD 16
#define FILL_CHUNK (FILL_BLOCK * FILL_PER_THREAD)               // 4096 elements
#define BLOCKS_PER_ROW ((NDOCS + FILL_CHUNK - 1) / FILL_CHUNK)  // 245 (tail=576)
#define QN (FILL_PER_THREAD / 4)                                // 4 int4 per thread
#define JTAB_W (BLOCKS_PER_ROW + 1)                             // 246 boundary entries/row

// -------- Kernel 1: per-row preprocessing (tiny) ------------------------
// Produces, per row b:
//   wsA[b*NPER + i]    = S[i] - i  (S = unique nonzero doc ids, ascending), i < nnz
//   wsHead[b*NPER + i] = i-th doc in (-score, id) order, i < nnz
//   wsNnz[b]           = nnz
//   wsJ[b*JTAB_W + c]  = count{A < c*FILL_CHUNK - nnz}  (per-chunk boundary table)
//   out_pos[b]         = head[pos_positions[b]]   (positive_idx output)
__global__ __launch_bounds__(512) void rrf_prep_kernel(
    const int* __restrict__ idx, const float* __restrict__ rnk,
    const float* __restrict__ weight, const int* __restrict__ pos,
    int* __restrict__ wsA, int* __restrict__ wsHead, int* __restrict__ wsNnz,
    int* __restrict__ wsJ, int* __restrict__ out_pos)
{
  const int b = blockIdx.x;
  const int tid = threadIdx.x;
  const int lane = tid & 63, wave = tid >> 6;

  __shared__ alignas(16) int   ids[NPER];
  __shared__ alignas(16) float sc[NPER];
  __shared__ alignas(16) int   sid[NPER];
  __shared__ alignas(16) float ssc[NPER];
  __shared__ alignas(16) int   uid[NPER];
  __shared__ alignas(16) float usc[NPER];
  __shared__ alignas(16) int   head[NPER];
  __shared__ int   wsum[8];

  // Load ids + compute rrf scores: w_t / (60 + rank)
  if (tid < NPER) {
    ids[tid] = idx[b * NPER + tid];
    sc[tid]  = weight[tid / K_DIM] / (60.0f + rnk[b * NPER + tid]);
  }
  __syncthreads();

  // Rank-sort by (id, original position) -> groups duplicates adjacently,
  // duplicate scores kept in original-position order for summation.
  // Vectorized: int4 LDS reads (4x fewer LDS-pipe ops; loop1 was LDS-bound).
  if (tid < NPER) {
    const int myid = ids[tid];
    int r = 0;
#pragma unroll 4
    for (int j4 = 0; j4 < NPER; j4 += 4) {
      const int4 o = *reinterpret_cast<const int4*>(&ids[j4]);
      r += (o.x < myid) || (o.x == myid && (j4 + 0) < tid);
      r += (o.y < myid) || (o.y == myid && (j4 + 1) < tid);
      r += (o.z < myid) || (o.z == myid && (j4 + 2) < tid);
      r += (o.w < myid) || (o.w == myid && (j4 + 3) < tid);
    }
    sid[r] = myid;
    ssc[r] = sc[tid];
  }
  __syncthreads();

  // Leaders sum their duplicate run (in original-position order).
  int isLeader = 0;
  float mysum = 0.0f;
  if (tid < NPER) {
    isLeader = (tid == 0) || (sid[tid] != sid[tid - 1]);
    if (isLeader) {
      mysum = ssc[tid];
      for (int k = tid + 1; k < NPER && sid[k] == sid[tid]; ++k) mysum += ssc[k];
    }
  }

  // Inclusive scan of isLeader over 512 threads: shuffle wave scan + combine.
  int val = isLeader;
#pragma unroll
  for (int off = 1; off < 64; off <<= 1) {
    int n = __shfl_up(val, off, 64);
    if (lane >= off) val += n;
  }
  if (lane == 63) wsum[wave] = val;
  __syncthreads();
  if (wave == 0 && lane < 8) {
    int wv = wsum[lane];
#pragma unroll
    for (int off = 1; off < 8; off <<= 1) {
      int n = __shfl_up(wv, off, 8);
      if ((lane & 7) >= off) wv += n;
    }
    wsum[lane] = wv;     // inclusive per-wave totals
  }
  __syncthreads();
  const int incl = val + (wave > 0 ? wsum[wave - 1] : 0);
  const int nnz  = wsum[7];

  if (isLeader) {
    const int u = incl - 1;        // compacted slot; ascending id order preserved
    uid[u] = sid[tid];
    usc[u] = mysum;
  }
  // Sentinel padding [nnz, NPER): lets the score rank-sort run a fixed,
  // fully-vectorized 400 iterations (sentinels never count: -1e30 < any score,
  // equality impossible).
  if (tid >= nnz && tid < NPER) {
    uid[tid] = 0x7fffffff;
    usc[tid] = -1e30f;
  }
  __syncthreads();

  // Rank-sort uniques by (-score, id asc) == stable argsort(-fused) order.
  if (tid < nnz) {
    const float si = usc[tid];
    const int   ii = uid[tid];
    int r2 = 0;
#pragma unroll 4
    for (int j4 = 0; j4 < NPER; j4 += 4) {
      const float4 s4 = *reinterpret_cast<const float4*>(&usc[j4]);
      const int4   u4 = *reinterpret_cast<const int4*>(&uid[j4]);
      r2 += (s4.x > si) || (s4.x == si && u4.x < ii);
      r2 += (s4.y > si) || (s4.y == si && u4.y < ii);
      r2 += (s4.z > si) || (s4.z == si && u4.z < ii);
      r2 += (s4.w > si) || (s4.w == si && u4.w < ii);
    }
    head[r2] = ii;
  }

  // Per-chunk boundary table: wsJ[b][c] = count{A < c*FILL_CHUNK - nnz},
  // A[i] = uid[i] - i (non-decreasing). One 9-step LDS binary search per
  // thread, 246 threads; lets fill's fast path skip LDS staging entirely.
  if (tid < JTAB_W) {
    const int z0 = tid * FILL_CHUNK - nnz;
    int lo = 0, hi = nnz;
    while (lo < hi) { const int mid = (lo + hi) >> 1; if (uid[mid] - mid < z0) lo = mid + 1; else hi = mid; }
    wsJ[b * JTAB_W + tid] = lo;
  }
  __syncthreads();

  if (tid < nnz) {
    wsA[b * NPER + tid]    = uid[tid] - tid;  // A[i] = S[i]-i, non-decreasing
    wsHead[b * NPER + tid] = head[tid];
  }
  if (tid == 0) {
    wsNnz[b]   = nnz;
    out_pos[b] = head[pos[b]];   // pos in [0,5), nnz >= ~396 always
  }
}

// -------- Kernel 2: write order[B, NDOCS] (the 240 MB store) ------------
// order[p] = head[p] for p < nnz; else z = p - nnz, doc = z + count{A[i] <= z}.
//
// Fast path (every chunk except 0, incl. tail): NO LDS, NO barrier.
//   j0 = wsJ[row][chunk]   = count{A < z0}          (block-uniform scalar load)
//   j1 = wsJ[row][chunk+1] = count{A <= z0+4095}    (adjacent -> one dwordx2)
//   out[p] = (z + j0) ramp, plus nb = j1-j0 (~1.6 avg) breakpoint compare-adds,
//   breakpoint values read uniformly from L2-hot wsA.
// Block critical path ~600 cycles (was ~2.5-3k with staging+sync+search),
// so the kernel approaches the pure store bound (240 MB @ ~6.6 TB/s ~= 36 us).
//
// Block-strided int4 layout: thread t's q-th int4 sits at int4-index
// chunk*1024 + q*256 + t -> each store instruction covers a contiguous
// 1 KB/wave (16 B/lane), full-line coverage, no RFO fetch.
// Normal (allocating) stores: 240 MB output fits the 256 MiB L3; writeback
// drains after kernel end, overlapped with subsequent stream work.
__global__ __launch_bounds__(FILL_BLOCK) void rrf_fill_kernel(
    const int* __restrict__ wsA, const int* __restrict__ wsHead,
    const int* __restrict__ wsNnz, const int* __restrict__ wsJ,
    int* __restrict__ out)
{
  const int row   = blockIdx.x / BLOCKS_PER_ROW;
  const int chunk = blockIdx.x % BLOCKS_PER_ROW;
  const int tid   = threadIdx.x;
  const int chunkbase = chunk * FILL_CHUNK;
  int* outrow = out + (long long)row * NDOCS;

  __shared__ int A[NPER];   // used by chunk-0 blocks only
  __shared__ int H[NPER];

  if (chunk != 0) {
    // Fast path: pure zero-tail (chunkbase >= 4096 > 400 >= nnz always).
    const int nnz = wsNnz[row];
    const int j0  = wsJ[row * JTAB_W + chunk];
    const int j1  = wsJ[row * JTAB_W + chunk + 1];   // count{A <= z0 + 4095}
    const int z0  = chunkbase - nnz;
    const int za  = z0 + tid * 4;                    // this thread's first z (q=0)

    int v[QN][4];
#pragma unroll
    for (int q = 0; q < QN; ++q) {
      const int bse = za + q * 1024 + j0;            // ramp base: z + j0
      v[q][0] = bse; v[q][1] = bse + 1; v[q][2] = bse + 2; v[q][3] = bse + 3;
    }
    // Breakpoint sweep: nb = j1-j0 (~1.6 avg) uniform L2-hot reads, 16 adds each.
    const int* __restrict__ Arow = wsA + row * NPER;
    for (int k = j0; k < j1; ++k) {
      const int a = Arow[k];
#pragma unroll
      for (int q = 0; q < QN; ++q) {
        const int z = za + q * 1024;
        v[q][0] += (a <= z);
        v[q][1] += (a <= z + 1);
        v[q][2] += (a <= z + 2);
        v[q][3] += (a <= z + 3);
      }
    }
#pragma unroll
    for (int q = 0; q < QN; ++q) {
      const int p0 = chunkbase + q * 1024 + tid * 4;
      if (p0 < NDOCS)                                // tail 576 = 144 int4, all-or-none
        *reinterpret_cast<int4*>(outrow + p0) =
            make_int4(v[q][0], v[q][1], v[q][2], v[q][3]);
    }
  } else {
    // Generic path: chunk 0 only (head region + its zero-tail), 60 blocks.
    __shared__ int s_nnz;
    for (int i = tid; i < NPER; i += FILL_BLOCK) {
      A[i] = wsA[row * NPER + i];        // entries >= nnz are garbage, never read
      H[i] = wsHead[row * NPER + i];
    }
    if (tid == 0) s_nnz = wsNnz[row];
    __syncthreads();
    const int nnz = s_nnz;

#pragma unroll
    for (int q = 0; q < QN; ++q) {
      const int p0 = q * 1024 + tid * 4;
      int vv[4];
#pragma unroll
      for (int k = 0; k < 4; ++k) {
        const int p = p0 + k;
        if (p < nnz) vv[k] = H[p];
        else {
          const int z = p - nnz;
          int lo = 0, hi = nnz;
          while (lo < hi) { const int mid = (lo + hi) >> 1; if (A[mid] <= z) lo = mid + 1; else hi = mid; }
          vv[k] = z + lo;
        }
      }
      *reinterpret_cast<int4*>(outrow + p0) = make_int4(vv[0], vv[1], vv[2], vv[3]);
    }
  }
}

extern "C" void kernel_launch(void* const* d_in, const int* in_sizes, int n_in,
                              void* d_out, int out_size, void* d_ws, size_t ws_size,
                              hipStream_t stream) {
  const int*   idx    = (const int*)d_in[0];    // [B,T,K] int32
  const float* rnk    = (const float*)d_in[1];  // [B,T,K] f32
  const float* weight = (const float*)d_in[2];  // [T] f32
  const int*   pos    = (const int*)d_in[3];    // [B] int32
  const int B = in_sizes[3];                    // 60

  int* out = (int*)d_out;                       // order[B*NDOCS] ++ positive_idx[B], int32
  int* ws  = (int*)d_ws;
  int* wsA    = ws;                             // B*NPER ints
  int* wsHead = ws + (size_t)B * NPER;          // B*NPER ints
  int* wsNnz  = ws + (size_t)2 * B * NPER;      // B ints
  int* wsJ    = wsNnz + B;                      // B*JTAB_W ints (~252 KB total ws)

  rrf_prep_kernel<<<B, 512, 0, stream>>>(idx, rnk, weight, pos,
                                         wsA, wsHead, wsNnz, wsJ,
                                         out + (size_t)B * NDOCS);
  rrf_fill_kernel<<<B * BLOCKS_PER_ROW, FILL_BLOCK, 0, stream>>>(wsA, wsHead, wsNnz, wsJ, out);
}